// Round 19
// baseline (249.087 us; speedup 1.0000x reference)
//
#include <hip/hip_runtime.h>
#include <math.h>

// ---------------------------------------------------------------------------
// GATv2 x2 on MI355X.
// Path:
//   memset(deg) -> k_count_deg (atomic rank capture) -> scan1/2/3
//   -> k_scatter_e (pos = rowptr+rank, atomic-free; ea_f16/qe2/src_perm)
//   -> k_wcvt (wcat transposed [n][k] bf16; we1h f16) -> k_gemm1_mfma
//   -> k_fused1_hw (HALF-WAVE: lanes 0-31 edge 2t, 32-63 edge 2t+1; lane owns
//      4 channels; 8-lane head reduce; fdot2 GEMV; prefetch)
//   -> k_fused2_q
// Round 19: fused1 half-wave pairing — per-edge fixed costs (gather, exp,
// reduce, unpack, loop) halve; ~115 -> ~40 wave-instr/edge.
// ---------------------------------------------------------------------------

typedef __attribute__((ext_vector_type(8))) short bf16x8;
typedef __attribute__((ext_vector_type(4))) float f32x4;
typedef __attribute__((ext_vector_type(2))) float f32x2;
typedef _Float16 f16;
typedef __attribute__((ext_vector_type(2))) _Float16 f16x2;
typedef __attribute__((ext_vector_type(8))) _Float16 f16x8;

static __device__ __forceinline__ ushort f2bf(float f) {
    unsigned u = __float_as_uint(f);
    unsigned r = (u + 0x7fffu + ((u >> 16) & 1u)) >> 16;  // RNE
    return (ushort)r;
}

// sum across each 16-lane row via DPP row_ror (pure VALU, no DS)
static __device__ __forceinline__ float row_sum16(float x) {
    x += __int_as_float(__builtin_amdgcn_update_dpp(0, __float_as_int(x), 0x121, 0xf, 0xf, true));
    x += __int_as_float(__builtin_amdgcn_update_dpp(0, __float_as_int(x), 0x122, 0xf, 0xf, true));
    x += __int_as_float(__builtin_amdgcn_update_dpp(0, __float_as_int(x), 0x124, 0xf, 0xf, true));
    x += __int_as_float(__builtin_amdgcn_update_dpp(0, __float_as_int(x), 0x128, 0xf, 0xf, true));
    return x;
}

// sum across each 8-lane group: quad xor1, xor2, then half-row mirror
static __device__ __forceinline__ float sum8(float x) {
    x += __int_as_float(__builtin_amdgcn_update_dpp(0, __float_as_int(x), 0xB1, 0xf, 0xf, true));   // quad_perm [1,0,3,2]
    x += __int_as_float(__builtin_amdgcn_update_dpp(0, __float_as_int(x), 0x4E, 0xf, 0xf, true));   // quad_perm [2,3,0,1]
    x += __int_as_float(__builtin_amdgcn_update_dpp(0, __float_as_int(x), 0x141, 0xf, 0xf, true));  // row_half_mirror
    return x;
}

// rank[i] = arrival order of edge i at its destination (used as CSR offset)
__global__ void k_count_deg(const int* __restrict__ dst, int* __restrict__ deg,
                            int* __restrict__ rank, int E) {
    int i = blockIdx.x * blockDim.x + threadIdx.x;
    if (i < E) rank[i] = atomicAdd(&deg[dst[i]], 1);
}

__global__ __launch_bounds__(1024) void k_scan1(const int* __restrict__ deg,
                                                int* __restrict__ rowptr,
                                                int* __restrict__ part, int N) {
    __shared__ int wsum[16];
    int t = threadIdx.x, l = t & 63, w = t >> 6;
    int i = blockIdx.x * 1024 + t;
    int v = (i < N) ? deg[i] : 0;
    int sc = v;
    #pragma unroll
    for (int off = 1; off < 64; off <<= 1) {
        int y = __shfl_up(sc, off);
        if (l >= off) sc += y;
    }
    if (l == 63) wsum[w] = sc;
    __syncthreads();
    if (w == 0) {
        int pv = (l < 16) ? wsum[l] : 0;
        int psc = pv;
        #pragma unroll
        for (int off = 1; off < 16; off <<= 1) {
            int y = __shfl_up(psc, off);
            if (l >= off) psc += y;
        }
        if (l < 16) wsum[l] = psc - pv;
    }
    __syncthreads();
    if (i < N) rowptr[i] = wsum[w] + sc - v;
    if (t == 1023) part[blockIdx.x] = wsum[15] + sc;
}

__global__ void k_scan2(int* __restrict__ part, int nb) {
    int l = threadIdx.x & 63;
    int run = 0;
    for (int base = 0; base < nb; base += 64) {
        int i = base + l;
        int v = (i < nb) ? part[i] : 0;
        int sc = v;
        #pragma unroll
        for (int off = 1; off < 64; off <<= 1) {
            int y = __shfl_up(sc, off);
            if (l >= off) sc += y;
        }
        if (i < nb) part[i] = run + sc - v;
        run += __shfl(sc, 63);
    }
}

__global__ void k_scan3(int* __restrict__ rowptr, const int* __restrict__ part, int N, int E) {
    int i = blockIdx.x * 256 + threadIdx.x;
    if (i < N) rowptr[i] += part[i >> 10];
    if (i == 0) rowptr[N] = E;
}

// scatter edges to CSR positions (pos = rowptr[dst] + rank, atomic-free):
// ea_f16[pos] (f16 x16), qe2[pos] = ea@We2 (f32 x4), src_perm[pos] = src.
__global__ __launch_bounds__(256) void k_scatter_e(
    const int* __restrict__ dst, const int* __restrict__ src,
    const float* __restrict__ ea, const float* __restrict__ We2,
    const int* __restrict__ rowptr, const int* __restrict__ rank,
    f16* __restrict__ ea_f16, float* __restrict__ qe2,
    int* __restrict__ src_perm, int E) {
    __shared__ float sW[64];
    int t = threadIdx.x;
    if (t < 64) sW[t] = We2[t];
    __syncthreads();
    int i = blockIdx.x * 256 + t;
    if (i >= E) return;
    int d = dst[i];
    int pos = rowptr[d] + rank[i];
    src_perm[pos] = src[i];
    const float4* s4 = (const float4*)(ea + (size_t)i * 16);
    float4 r0 = s4[0], r1 = s4[1], r2 = s4[2], r3 = s4[3];
    f16x8 h0, h1;
    h0[0] = (f16)r0.x; h0[1] = (f16)r0.y; h0[2] = (f16)r0.z; h0[3] = (f16)r0.w;
    h0[4] = (f16)r1.x; h0[5] = (f16)r1.y; h0[6] = (f16)r1.z; h0[7] = (f16)r1.w;
    h1[0] = (f16)r2.x; h1[1] = (f16)r2.y; h1[2] = (f16)r2.z; h1[3] = (f16)r2.w;
    h1[4] = (f16)r3.x; h1[5] = (f16)r3.y; h1[6] = (f16)r3.z; h1[7] = (f16)r3.w;
    *(f16x8*)(ea_f16 + (size_t)pos * 16) = h0;
    *(f16x8*)(ea_f16 + (size_t)pos * 16 + 8) = h1;
    float a[16] = {r0.x, r0.y, r0.z, r0.w, r1.x, r1.y, r1.z, r1.w,
                   r2.x, r2.y, r2.z, r2.w, r3.x, r3.y, r3.z, r3.w};
    float q0 = 0.f, q1 = 0.f, q2v = 0.f, q3 = 0.f;
    #pragma unroll
    for (int k = 0; k < 16; ++k) {
        q0 += a[k] * sW[k * 4 + 0];
        q1 += a[k] * sW[k * 4 + 1];
        q2v += a[k] * sW[k * 4 + 2];
        q3 += a[k] * sW[k * 4 + 3];
    }
    *(float4*)(qe2 + (size_t)pos * 4) = make_float4(q0, q1, q2v, q3);
}

// wcat_t[n][k] (bf16, 256x128) = [Wl1 | Wr1]^T; we1h = f16 We1 (16x128)
__global__ void k_wcvt(const float* __restrict__ Wl, const float* __restrict__ Wr,
                       const float* __restrict__ We1,
                       ushort* __restrict__ wcat_t, f16* __restrict__ we1h) {
    int i = blockIdx.x * 256 + threadIdx.x;
    if (i < 16 * 128) we1h[i] = (f16)We1[i];
    if (i >= 128 * 256) return;
    int n = i >> 7, k = i & 127;
    float v = (n < 128) ? Wl[k * 128 + n] : Wr[k * 128 + (n - 128)];
    wcat_t[i] = f2bf(v);
}

// xl1 = x@Wl1 (bf16 out), xr1 = x@Wr1 (f32 out) via MFMA bf16.
__global__ __launch_bounds__(256) void k_gemm1_mfma(
    const float* __restrict__ x, const ushort* __restrict__ wcat_t,
    ushort* __restrict__ xl, float* __restrict__ xr, int N) {
    __shared__ ushort xs[64 * 128];  // 16 KB, swizzled
    int t = threadIdx.x, l = t & 63, w = t >> 6;
    int r0 = blockIdx.x * 64;
    bf16x8 bf[4][4];
    {
        int coln = w * 64 + (l & 15);
        int kr = (l >> 4) * 8;
        #pragma unroll
        for (int nt = 0; nt < 4; ++nt)
            #pragma unroll
            for (int ks = 0; ks < 4; ++ks)
                bf[nt][ks] = *(const bf16x8*)&wcat_t[(size_t)(nt * 16 + coln) * 128 + ks * 32 + kr];
    }
    #pragma unroll
    for (int it = 0; it < 4; ++it) {
        int slot = t + 256 * it;        // 1024 slots = 64 rows x 16 chunks
        int row = slot >> 4, ch = slot & 15;
        int grow = r0 + row;
        float v0 = 0.f, v1 = 0.f, v2 = 0.f, v3 = 0.f, v4 = 0.f, v5 = 0.f, v6 = 0.f, v7 = 0.f;
        if (grow < N) {
            float4 a = *(const float4*)(x + (size_t)grow * 128 + ch * 8);
            float4 b = *(const float4*)(x + (size_t)grow * 128 + ch * 8 + 4);
            v0 = a.x; v1 = a.y; v2 = a.z; v3 = a.w;
            v4 = b.x; v5 = b.y; v6 = b.z; v7 = b.w;
        }
        bf16x8 tv;
        tv[0] = (short)f2bf(v0); tv[1] = (short)f2bf(v1);
        tv[2] = (short)f2bf(v2); tv[3] = (short)f2bf(v3);
        tv[4] = (short)f2bf(v4); tv[5] = (short)f2bf(v5);
        tv[6] = (short)f2bf(v6); tv[7] = (short)f2bf(v7);
        int ch2 = ch ^ (row & 15);
        *(bf16x8*)&xs[row * 128 + ch2 * 8] = tv;
    }
    __syncthreads();
    f32x4 acc[4][4];
    #pragma unroll
    for (int mt = 0; mt < 4; ++mt)
        #pragma unroll
        for (int nt = 0; nt < 4; ++nt)
            acc[mt][nt] = (f32x4){0.f, 0.f, 0.f, 0.f};
    #pragma unroll
    for (int ks = 0; ks < 4; ++ks) {
        bf16x8 af[4];
        #pragma unroll
        for (int mt = 0; mt < 4; ++mt) {
            int row = mt * 16 + (l & 15);
            int ch = (ks * 4 + (l >> 4)) ^ (row & 15);
            af[mt] = *(const bf16x8*)&xs[row * 128 + ch * 8];
        }
        #pragma unroll
        for (int mt = 0; mt < 4; ++mt)
            #pragma unroll
            for (int nt = 0; nt < 4; ++nt)
                acc[mt][nt] = __builtin_amdgcn_mfma_f32_16x16x32_bf16(
                    af[mt], bf[nt][ks], acc[mt][nt], 0, 0, 0);
    }
    #pragma unroll
    for (int mt = 0; mt < 4; ++mt) {
        #pragma unroll
        for (int nt = 0; nt < 4; ++nt) {
            int colg = w * 64 + nt * 16 + (l & 15);
            #pragma unroll
            for (int r = 0; r < 4; ++r) {
                int rowg = r0 + mt * 16 + (l >> 4) * 4 + r;
                if (rowg < N) {
                    float val = acc[mt][nt][r];
                    if (colg < 128) xl[(size_t)rowg * 128 + colg] = f2bf(val);
                    else            xr[(size_t)rowg * 128 + (colg - 128)] = val;
                }
            }
        }
    }
}

// layer 1 fused, HALF-WAVE: lanes 0-31 handle edge 2t, lanes 32-63 edge 2t+1.
// Lane j=l&31 owns channels 4j..4j+3. Head h = lanes 8h..8h+7 (sum8 reduce).
__global__ __launch_bounds__(256) void k_fused1_hw(
    const int* __restrict__ rowptr, const int* __restrict__ src_perm,
    const ushort* __restrict__ xl_bf, const float* __restrict__ xr,
    const f16* __restrict__ ea_f16, const f16* __restrict__ we1h,
    const float* __restrict__ att,
    const float* __restrict__ Wl2, const float* __restrict__ Wr2,
    float* __restrict__ xl2, float* __restrict__ xr2, int N) {
    int t = threadIdx.x, l = t & 63;
    int j = l & 31, half = l >> 5;
    int n = (blockIdx.x * 256 + t) >> 6;
    if (n >= N) return;
    const float RLN2 = 1.44269504f;
    const unsigned* xlw = (const unsigned*)xl_bf;  // [node*64 + dword]
    // weights: w16[c][kp] = (We1[2kp][4j+c], We1[2kp+1][4j+c])
    f16x2 w16[4][8];
    #pragma unroll
    for (int c = 0; c < 4; ++c)
        #pragma unroll
        for (int kp = 0; kp < 8; ++kp) {
            w16[c][kp][0] = we1h[(2 * kp) * 128 + 4 * j + c];
            w16[c][kp][1] = we1h[(2 * kp + 1) * 128 + 4 * j + c];
        }
    float4 av = *(const float4*)(att + 4 * j);
    av.x *= RLN2; av.y *= RLN2; av.z *= RLN2; av.w *= RLN2;
    float4 xrv = *(const float4*)(xr + (size_t)n * 128 + 4 * j);
    int rs = rowptr[n], re = rowptr[n + 1];
    int deg = re - rs;
    int urs = __builtin_amdgcn_readfirstlane(rs);
    float acc0 = 0.f, acc1 = 0.f, acc2 = 0.f, acc3 = 0.f;
    float mq0 = 0.f, mq1 = 0.f, mq2 = 0.f, mq3 = 0.f;
    float den = 0.f;
    int niter = (deg + 1) >> 1;
    float mk_nxt = 0.f;
    unsigned jj_nxt = 0;
    uint2 xw_nxt = make_uint2(0u, 0u);
    if (niter > 0) {
        int sA = half;
        mk_nxt = (sA < deg) ? 1.f : 0.f;
        int sc = (sA < deg) ? sA : (deg - 1);
        jj_nxt = (unsigned)(urs + sc);
        int s0 = src_perm[jj_nxt];
        xw_nxt = *(const uint2*)(xlw + (size_t)(unsigned)s0 * 64u + 2u * j);
    }
    for (int it = 0; it < niter; ++it) {
        float mk = mk_nxt;
        unsigned jj = jj_nxt;
        uint2 xw = xw_nxt;
        if (it + 1 < niter) {
            int sA = 2 * (it + 1) + half;
            mk_nxt = (sA < deg) ? 1.f : 0.f;
            int sc = (sA < deg) ? sA : (deg - 1);
            jj_nxt = (unsigned)(urs + sc);
            int s1 = src_perm[jj_nxt];
            xw_nxt = *(const uint2*)(xlw + (size_t)(unsigned)s1 * 64u + 2u * j);
        }
        const f16x2* ap = (const f16x2*)(ea_f16 + (size_t)jj * 16);  // per-half addr
        float q0 = 0.f, q1 = 0.f, q2 = 0.f, q3 = 0.f;
        #pragma unroll
        for (int kp = 0; kp < 8; ++kp) {
            f16x2 a = ap[kp];
            q0 = __builtin_amdgcn_fdot2(a, w16[0][kp], q0, false);
            q1 = __builtin_amdgcn_fdot2(a, w16[1][kp], q1, false);
            q2 = __builtin_amdgcn_fdot2(a, w16[2][kp], q2, false);
            q3 = __builtin_amdgcn_fdot2(a, w16[3][kp], q3, false);
        }
        float x0 = __uint_as_float(xw.x << 16);
        float x1 = __uint_as_float(xw.x & 0xffff0000u);
        float x2 = __uint_as_float(xw.y << 16);
        float x3 = __uint_as_float(xw.y & 0xffff0000u);
        float v0 = xrv.x + q0 + x0;
        float v1 = xrv.y + q1 + x1;
        float v2 = xrv.z + q2 + x2;
        float v3 = xrv.w + q3 + x3;
        v0 = fmaxf(v0, 0.2f * v0);
        v1 = fmaxf(v1, 0.2f * v1);
        v2 = fmaxf(v2, 0.2f * v2);
        v3 = fmaxf(v3, 0.2f * v3);
        float p = av.x * v0 + av.y * v1 + av.z * v2 + av.w * v3;
        p = sum8(p);
        float w = exp2f(p) * mk;
        acc0 += w * x0; acc1 += w * x1; acc2 += w * x2; acc3 += w * x3;
        den += w;
        mq0 += mk * q0; mq1 += mk * q1; mq2 += mk * q2; mq3 += mk * q3;
    }
    // combine halves (each lane then holds full-edge totals for its channels)
    acc0 += __shfl_xor(acc0, 32); acc1 += __shfl_xor(acc1, 32);
    acc2 += __shfl_xor(acc2, 32); acc3 += __shfl_xor(acc3, 32);
    mq0 += __shfl_xor(mq0, 32); mq1 += __shfl_xor(mq1, 32);
    mq2 += __shfl_xor(mq2, 32); mq3 += __shfl_xor(mq3, 32);
    den += __shfl_xor(den, 32);
    {   // self loop: q_self = mean of incoming q (= loop_attr @ We1)
        float inv = 1.f / (float)(deg > 1 ? deg : 1);
        float q0 = mq0 * inv, q1 = mq1 * inv, q2 = mq2 * inv, q3 = mq3 * inv;
        uint2 xw = *(const uint2*)(xlw + (size_t)(unsigned)n * 64u + 2u * j);
        float x0 = __uint_as_float(xw.x << 16);
        float x1 = __uint_as_float(xw.x & 0xffff0000u);
        float x2 = __uint_as_float(xw.y << 16);
        float x3 = __uint_as_float(xw.y & 0xffff0000u);
        float v0 = xrv.x + q0 + x0;
        float v1 = xrv.y + q1 + x1;
        float v2 = xrv.z + q2 + x2;
        float v3 = xrv.w + q3 + x3;
        v0 = fmaxf(v0, 0.2f * v0);
        v1 = fmaxf(v1, 0.2f * v1);
        v2 = fmaxf(v2, 0.2f * v2);
        v3 = fmaxf(v3, 0.2f * v3);
        float p = av.x * v0 + av.y * v1 + av.z * v2 + av.w * v3;
        p = sum8(p);
        float w = exp2f(p);
        acc0 += w * x0; acc1 += w * x1; acc2 += w * x2; acc3 += w * x3;
        den += w;
    }
    float rdn = 1.f / (den + 1e-16f);
    float h0 = acc0 * rdn, h1 = acc1 * rdn, h2 = acc2 * rdn, h3 = acc3 * rdn;
    h0 = h0 > 0.f ? h0 : 0.01f * h0;
    h1 = h1 > 0.f ? h1 : 0.01f * h1;
    h2 = h2 > 0.f ? h2 : 0.01f * h2;
    h3 = h3 > 0.f ? h3 : 0.01f * h3;
    // gemv2: lane j covers rows 4j..4j+3 of Wl2/Wr2 (halves duplicate)
    float4 wl0 = *(const float4*)(Wl2 + (size_t)(4 * j + 0) * 4);
    float4 wl1 = *(const float4*)(Wl2 + (size_t)(4 * j + 1) * 4);
    float4 wl2v = *(const float4*)(Wl2 + (size_t)(4 * j + 2) * 4);
    float4 wl3 = *(const float4*)(Wl2 + (size_t)(4 * j + 3) * 4);
    float4 wr0 = *(const float4*)(Wr2 + (size_t)(4 * j + 0) * 4);
    float4 wr1 = *(const float4*)(Wr2 + (size_t)(4 * j + 1) * 4);
    float4 wr2v = *(const float4*)(Wr2 + (size_t)(4 * j + 2) * 4);
    float4 wr3 = *(const float4*)(Wr2 + (size_t)(4 * j + 3) * 4);
    float q0 = h0 * wl0.x + h1 * wl1.x + h2 * wl2v.x + h3 * wl3.x;
    float q1 = h0 * wl0.y + h1 * wl1.y + h2 * wl2v.y + h3 * wl3.y;
    float q2 = h0 * wl0.z + h1 * wl1.z + h2 * wl2v.z + h3 * wl3.z;
    float q3 = h0 * wl0.w + h1 * wl1.w + h2 * wl2v.w + h3 * wl3.w;
    float q4 = h0 * wr0.x + h1 * wr1.x + h2 * wr2v.x + h3 * wr3.x;
    float q5 = h0 * wr0.y + h1 * wr1.y + h2 * wr2v.y + h3 * wr3.y;
    float q6 = h0 * wr0.z + h1 * wr1.z + h2 * wr2v.z + h3 * wr3.z;
    float q7 = h0 * wr0.w + h1 * wr1.w + h2 * wr2v.w + h3 * wr3.w;
    // reduce over lanes 0..31 (halves duplicate -> do NOT add across halves)
    q0 = row_sum16(q0); q0 += __shfl_xor(q0, 16);
    q1 = row_sum16(q1); q1 += __shfl_xor(q1, 16);
    q2 = row_sum16(q2); q2 += __shfl_xor(q2, 16);
    q3 = row_sum16(q3); q3 += __shfl_xor(q3, 16);
    q4 = row_sum16(q4); q4 += __shfl_xor(q4, 16);
    q5 = row_sum16(q5); q5 += __shfl_xor(q5, 16);
    q6 = row_sum16(q6); q6 += __shfl_xor(q6, 16);
    q7 = row_sum16(q7); q7 += __shfl_xor(q7, 16);
    if (l == 0) {
        *(float4*)(xl2 + (size_t)n * 4) = make_float4(q0, q1, q2, q3);
        *(float4*)(xr2 + (size_t)n * 4) = make_float4(q4, q5, q6, q7);
    }
}

// layer 2 fused: 16 lanes per node, self-term = in-loop mean of qe2
__global__ __launch_bounds__(256, 4) void k_fused2_q(
    const int* __restrict__ rowptr, const int* __restrict__ src_perm,
    const float* __restrict__ xl2, const float* __restrict__ xr2,
    const float* __restrict__ qe2, const float* __restrict__ att2,
    float* __restrict__ out, int N) {
    int t = threadIdx.x, l = t & 63, g = l & 15;
    int node = (((blockIdx.x * 256 + t) >> 6) << 2) + (l >> 4);
    if (node >= N) return;
    int rs = rowptr[node], re = rowptr[node + 1];
    int deg = re - rs;
    float4 xrv = *(const float4*)(xr2 + (size_t)node * 4);
    const float RLN2 = 1.44269504f;
    float a0 = att2[0] * RLN2, a1 = att2[1] * RLN2;
    float a2 = att2[2] * RLN2, a3 = att2[3] * RLN2;
    float ac0 = 0.f, ac1 = 0.f, ac2 = 0.f, ac3 = 0.f;
    float dn0 = 0.f, dn1 = 0.f, dn2 = 0.f, dn3 = 0.f;
    float mq0 = 0.f, mq1 = 0.f, mq2 = 0.f, mq3 = 0.f;
    for (int slot = g; slot < deg; slot += 16) {
        int row = rs + slot;
        int s = src_perm[row];
        float4 q = *(const float4*)(qe2 + (size_t)row * 4);
        float4 xv = *(const float4*)(xl2 + (size_t)s * 4);
        float v0 = xv.x + xrv.x + q.x; v0 = fmaxf(v0, 0.2f * v0);
        float v1 = xv.y + xrv.y + q.y; v1 = fmaxf(v1, 0.2f * v1);
        float v2 = xv.z + xrv.z + q.z; v2 = fmaxf(v2, 0.2f * v2);
        float v3 = xv.w + xrv.w + q.w; v3 = fmaxf(v3, 0.2f * v3);
        float w0 = exp2f(v0 * a0); ac0 += w0 * xv.x; dn0 += w0;
        float w1 = exp2f(v1 * a1); ac1 += w1 * xv.y; dn1 += w1;
        float w2 = exp2f(v2 * a2); ac2 += w2 * xv.z; dn2 += w2;
        float w3 = exp2f(v3 * a3); ac3 += w3 * xv.w; dn3 += w3;
        mq0 += q.x; mq1 += q.y; mq2 += q.z; mq3 += q.w;
    }
    ac0 = row_sum16(ac0); ac1 = row_sum16(ac1);
    ac2 = row_sum16(ac2); ac3 = row_sum16(ac3);
    dn0 = row_sum16(dn0); dn1 = row_sum16(dn1);
    dn2 = row_sum16(dn2); dn3 = row_sum16(dn3);
    mq0 = row_sum16(mq0); mq1 = row_sum16(mq1);
    mq2 = row_sum16(mq2); mq3 = row_sum16(mq3);
    {   // self loop (uniform across the 16-lane group)
        float inv = 1.f / (float)(deg > 1 ? deg : 1);
        float4 xv = *(const float4*)(xl2 + (size_t)node * 4);
        float v0 = xv.x + xrv.x + mq0 * inv; v0 = fmaxf(v0, 0.2f * v0);
        float v1 = xv.y + xrv.y + mq1 * inv; v1 = fmaxf(v1, 0.2f * v1);
        float v2 = xv.z + xrv.z + mq2 * inv; v2 = fmaxf(v2, 0.2f * v2);
        float v3 = xv.w + xrv.w + mq3 * inv; v3 = fmaxf(v3, 0.2f * v3);
        float w0 = exp2f(v0 * a0); ac0 += w0 * xv.x; dn0 += w0;
        float w1 = exp2f(v1 * a1); ac1 += w1 * xv.y; dn1 += w1;
        float w2 = exp2f(v2 * a2); ac2 += w2 * xv.z; dn2 += w2;
        float w3 = exp2f(v3 * a3); ac3 += w3 * xv.w; dn3 += w3;
    }
    if (g == 0) {
        float r = ac0 / (dn0 + 1e-16f) + ac1 / (dn1 + 1e-16f)
                + ac2 / (dn2 + 1e-16f) + ac3 / (dn3 + 1e-16f);
        out[node] = r * 0.25f;
    }
}

extern "C" void kernel_launch(void* const* d_in, const int* in_sizes, int n_in,
                              void* d_out, int out_size, void* d_ws, size_t ws_size,
                              hipStream_t stream) {
    const float* x         = (const float*)d_in[0];
    const int*   edge_index= (const int*)d_in[1];
    const float* edge_attr = (const float*)d_in[2];
    const float* Wl1       = (const float*)d_in[3];
    const float* Wr1       = (const float*)d_in[4];
    const float* We1       = (const float*)d_in[5];
    const float* att1      = (const float*)d_in[6];
    const float* Wl2       = (const float*)d_in[7];
    const float* Wr2       = (const float*)d_in[8];
    const float* We2       = (const float*)d_in[9];
    const float* att2      = (const float*)d_in[10];
    float* outp = (float*)d_out;

    const int F = 128, HC = 128;
    int N = in_sizes[0] / F;
    int E = in_sizes[1] / 2;
    const int* src = edge_index;
    const int* dst = edge_index + E;

    char* ws = (char*)d_ws;
    size_t off = 0;
    auto alloc = [&](size_t bytes) {
        char* p = ws + off;
        off += (bytes + 255) & ~(size_t)255;
        return p;
    };
    int*      deg      = (int*)alloc((size_t)N * 4);
    int*      rowptr   = (int*)alloc((size_t)(N + 1) * 4);
    int*      part     = (int*)alloc(((size_t)N / 1024 + 2) * 4);
    int*      rank     = (int*)alloc((size_t)E * 4);
    ushort*   wcat_t   = (ushort*)alloc((size_t)128 * 256 * 2);
    f16*      we1h     = (f16*)alloc((size_t)16 * 128 * 2);
    ushort*   xl_bf    = (ushort*)alloc((size_t)N * HC * 2);
    float*    xr1      = (float*)alloc((size_t)N * HC * 4);
    float*    xl2      = (float*)alloc((size_t)N * 4 * 4);
    float*    xr2      = (float*)alloc((size_t)N * 4 * 4);
    int*      src_perm = (int*)alloc((size_t)E * 4);
    float*    qe2      = (float*)alloc((size_t)E * 4 * 4);
    f16*      ea_f16   = (f16*)alloc((size_t)E * 16 * 2);

    int eb = (E + 255) / 256;
    int nb = (N + 1023) / 1024;

    hipMemsetAsync(deg, 0, (size_t)N * 4, stream);
    k_count_deg<<<eb, 256, 0, stream>>>(dst, deg, rank, E);
    k_scan1<<<nb, 1024, 0, stream>>>(deg, rowptr, part, N);
    k_scan2<<<1, 64, 0, stream>>>(part, nb);
    k_scan3<<<(N + 255) / 256, 256, 0, stream>>>(rowptr, part, N, E);
    k_scatter_e<<<eb, 256, 0, stream>>>(dst, src, edge_attr, We2, rowptr, rank,
                                        ea_f16, qe2, src_perm, E);
    k_wcvt<<<128, 256, 0, stream>>>(Wl1, Wr1, We1, wcat_t, we1h);
    k_gemm1_mfma<<<(N + 63) / 64, 256, 0, stream>>>(x, wcat_t, xl_bf, xr1, N);
    k_fused1_hw<<<(N + 3) / 4, 256, 0, stream>>>(rowptr, src_perm, xl_bf, xr1, ea_f16,
                                                 we1h, att1, Wl2, Wr2, xl2, xr2, N);
    k_fused2_q<<<(N + 15) / 16, 256, 0, stream>>>(rowptr, src_perm, xl2, xr2, qe2,
                                                  att2, outp, N);
}

// Round 20
// 211.289 us; speedup vs baseline: 1.1789x; 1.1789x over previous
//
#include <hip/hip_runtime.h>
#include <math.h>

// ---------------------------------------------------------------------------
// GATv2 x2 on MI355X.
// Path:
//   memset(deg) -> k_count_deg (atomic rank capture) -> scan1/2/3
//   -> k_scatter_e (pos = rowptr+rank, atomic-free; ea_f16/qe2/src_perm)
//   -> k_wcvt (wcat transposed [n][k] bf16; we1h f16) -> k_gemm1_mfma
//   -> k_fused1_dot (in-loop qe1 via fdot2; depth-2 prefetch: src two slots
//      ahead, xl gather one slot ahead) -> k_fused2_q
// Round 20: r19 half-wave reverted (VGPR 44 + divergent ea loads -> 137us).
// r18 base + decoupled src/gather prefetch chain.
// ---------------------------------------------------------------------------

typedef __attribute__((ext_vector_type(8))) short bf16x8;
typedef __attribute__((ext_vector_type(4))) float f32x4;
typedef __attribute__((ext_vector_type(2))) float f32x2;
typedef _Float16 f16;
typedef __attribute__((ext_vector_type(2))) _Float16 f16x2;
typedef __attribute__((ext_vector_type(8))) _Float16 f16x8;

static __device__ __forceinline__ ushort f2bf(float f) {
    unsigned u = __float_as_uint(f);
    unsigned r = (u + 0x7fffu + ((u >> 16) & 1u)) >> 16;  // RNE
    return (ushort)r;
}

// sum across each 16-lane row via DPP row_ror (pure VALU, no DS)
static __device__ __forceinline__ float row_sum16(float x) {
    x += __int_as_float(__builtin_amdgcn_update_dpp(0, __float_as_int(x), 0x121, 0xf, 0xf, true));
    x += __int_as_float(__builtin_amdgcn_update_dpp(0, __float_as_int(x), 0x122, 0xf, 0xf, true));
    x += __int_as_float(__builtin_amdgcn_update_dpp(0, __float_as_int(x), 0x124, 0xf, 0xf, true));
    x += __int_as_float(__builtin_amdgcn_update_dpp(0, __float_as_int(x), 0x128, 0xf, 0xf, true));
    return x;
}

static __device__ __forceinline__ float red64(float x) {  // 64-lane sum
    x = row_sum16(x);
    x += __shfl_xor(x, 16);
    x += __shfl_xor(x, 32);
    return x;
}

// rank[i] = arrival order of edge i at its destination (used as CSR offset)
__global__ void k_count_deg(const int* __restrict__ dst, int* __restrict__ deg,
                            int* __restrict__ rank, int E) {
    int i = blockIdx.x * blockDim.x + threadIdx.x;
    if (i < E) rank[i] = atomicAdd(&deg[dst[i]], 1);
}

__global__ __launch_bounds__(1024) void k_scan1(const int* __restrict__ deg,
                                                int* __restrict__ rowptr,
                                                int* __restrict__ part, int N) {
    __shared__ int wsum[16];
    int t = threadIdx.x, l = t & 63, w = t >> 6;
    int i = blockIdx.x * 1024 + t;
    int v = (i < N) ? deg[i] : 0;
    int sc = v;
    #pragma unroll
    for (int off = 1; off < 64; off <<= 1) {
        int y = __shfl_up(sc, off);
        if (l >= off) sc += y;
    }
    if (l == 63) wsum[w] = sc;
    __syncthreads();
    if (w == 0) {
        int pv = (l < 16) ? wsum[l] : 0;
        int psc = pv;
        #pragma unroll
        for (int off = 1; off < 16; off <<= 1) {
            int y = __shfl_up(psc, off);
            if (l >= off) psc += y;
        }
        if (l < 16) wsum[l] = psc - pv;
    }
    __syncthreads();
    if (i < N) rowptr[i] = wsum[w] + sc - v;
    if (t == 1023) part[blockIdx.x] = wsum[15] + sc;
}

__global__ void k_scan2(int* __restrict__ part, int nb) {
    int l = threadIdx.x & 63;
    int run = 0;
    for (int base = 0; base < nb; base += 64) {
        int i = base + l;
        int v = (i < nb) ? part[i] : 0;
        int sc = v;
        #pragma unroll
        for (int off = 1; off < 64; off <<= 1) {
            int y = __shfl_up(sc, off);
            if (l >= off) sc += y;
        }
        if (i < nb) part[i] = run + sc - v;
        run += __shfl(sc, 63);
    }
}

__global__ void k_scan3(int* __restrict__ rowptr, const int* __restrict__ part, int N, int E) {
    int i = blockIdx.x * 256 + threadIdx.x;
    if (i < N) rowptr[i] += part[i >> 10];
    if (i == 0) rowptr[N] = E;
}

// scatter edges to CSR positions (pos = rowptr[dst] + rank, atomic-free):
// ea_f16[pos] (f16 x16), qe2[pos] = ea@We2 (f32 x4), src_perm[pos] = src.
__global__ __launch_bounds__(256) void k_scatter_e(
    const int* __restrict__ dst, const int* __restrict__ src,
    const float* __restrict__ ea, const float* __restrict__ We2,
    const int* __restrict__ rowptr, const int* __restrict__ rank,
    f16* __restrict__ ea_f16, float* __restrict__ qe2,
    int* __restrict__ src_perm, int E) {
    __shared__ float sW[64];
    int t = threadIdx.x;
    if (t < 64) sW[t] = We2[t];
    __syncthreads();
    int i = blockIdx.x * 256 + t;
    if (i >= E) return;
    int d = dst[i];
    int pos = rowptr[d] + rank[i];
    src_perm[pos] = src[i];
    const float4* s4 = (const float4*)(ea + (size_t)i * 16);
    float4 r0 = s4[0], r1 = s4[1], r2 = s4[2], r3 = s4[3];
    f16x8 h0, h1;
    h0[0] = (f16)r0.x; h0[1] = (f16)r0.y; h0[2] = (f16)r0.z; h0[3] = (f16)r0.w;
    h0[4] = (f16)r1.x; h0[5] = (f16)r1.y; h0[6] = (f16)r1.z; h0[7] = (f16)r1.w;
    h1[0] = (f16)r2.x; h1[1] = (f16)r2.y; h1[2] = (f16)r2.z; h1[3] = (f16)r2.w;
    h1[4] = (f16)r3.x; h1[5] = (f16)r3.y; h1[6] = (f16)r3.z; h1[7] = (f16)r3.w;
    *(f16x8*)(ea_f16 + (size_t)pos * 16) = h0;
    *(f16x8*)(ea_f16 + (size_t)pos * 16 + 8) = h1;
    float a[16] = {r0.x, r0.y, r0.z, r0.w, r1.x, r1.y, r1.z, r1.w,
                   r2.x, r2.y, r2.z, r2.w, r3.x, r3.y, r3.z, r3.w};
    float q0 = 0.f, q1 = 0.f, q2v = 0.f, q3 = 0.f;
    #pragma unroll
    for (int k = 0; k < 16; ++k) {
        q0 += a[k] * sW[k * 4 + 0];
        q1 += a[k] * sW[k * 4 + 1];
        q2v += a[k] * sW[k * 4 + 2];
        q3 += a[k] * sW[k * 4 + 3];
    }
    *(float4*)(qe2 + (size_t)pos * 4) = make_float4(q0, q1, q2v, q3);
}

// wcat_t[n][k] (bf16, 256x128) = [Wl1 | Wr1]^T; we1h = f16 We1 (16x128)
__global__ void k_wcvt(const float* __restrict__ Wl, const float* __restrict__ Wr,
                       const float* __restrict__ We1,
                       ushort* __restrict__ wcat_t, f16* __restrict__ we1h) {
    int i = blockIdx.x * 256 + threadIdx.x;
    if (i < 16 * 128) we1h[i] = (f16)We1[i];
    if (i >= 128 * 256) return;
    int n = i >> 7, k = i & 127;
    float v = (n < 128) ? Wl[k * 128 + n] : Wr[k * 128 + (n - 128)];
    wcat_t[i] = f2bf(v);
}

// xl1 = x@Wl1 (bf16 out), xr1 = x@Wr1 (f32 out) via MFMA bf16.
__global__ __launch_bounds__(256) void k_gemm1_mfma(
    const float* __restrict__ x, const ushort* __restrict__ wcat_t,
    ushort* __restrict__ xl, float* __restrict__ xr, int N) {
    __shared__ ushort xs[64 * 128];  // 16 KB, swizzled
    int t = threadIdx.x, l = t & 63, w = t >> 6;
    int r0 = blockIdx.x * 64;
    bf16x8 bf[4][4];
    {
        int coln = w * 64 + (l & 15);
        int kr = (l >> 4) * 8;
        #pragma unroll
        for (int nt = 0; nt < 4; ++nt)
            #pragma unroll
            for (int ks = 0; ks < 4; ++ks)
                bf[nt][ks] = *(const bf16x8*)&wcat_t[(size_t)(nt * 16 + coln) * 128 + ks * 32 + kr];
    }
    #pragma unroll
    for (int it = 0; it < 4; ++it) {
        int slot = t + 256 * it;        // 1024 slots = 64 rows x 16 chunks
        int row = slot >> 4, ch = slot & 15;
        int grow = r0 + row;
        float v0 = 0.f, v1 = 0.f, v2 = 0.f, v3 = 0.f, v4 = 0.f, v5 = 0.f, v6 = 0.f, v7 = 0.f;
        if (grow < N) {
            float4 a = *(const float4*)(x + (size_t)grow * 128 + ch * 8);
            float4 b = *(const float4*)(x + (size_t)grow * 128 + ch * 8 + 4);
            v0 = a.x; v1 = a.y; v2 = a.z; v3 = a.w;
            v4 = b.x; v5 = b.y; v6 = b.z; v7 = b.w;
        }
        bf16x8 tv;
        tv[0] = (short)f2bf(v0); tv[1] = (short)f2bf(v1);
        tv[2] = (short)f2bf(v2); tv[3] = (short)f2bf(v3);
        tv[4] = (short)f2bf(v4); tv[5] = (short)f2bf(v5);
        tv[6] = (short)f2bf(v6); tv[7] = (short)f2bf(v7);
        int ch2 = ch ^ (row & 15);
        *(bf16x8*)&xs[row * 128 + ch2 * 8] = tv;
    }
    __syncthreads();
    f32x4 acc[4][4];
    #pragma unroll
    for (int mt = 0; mt < 4; ++mt)
        #pragma unroll
        for (int nt = 0; nt < 4; ++nt)
            acc[mt][nt] = (f32x4){0.f, 0.f, 0.f, 0.f};
    #pragma unroll
    for (int ks = 0; ks < 4; ++ks) {
        bf16x8 af[4];
        #pragma unroll
        for (int mt = 0; mt < 4; ++mt) {
            int row = mt * 16 + (l & 15);
            int ch = (ks * 4 + (l >> 4)) ^ (row & 15);
            af[mt] = *(const bf16x8*)&xs[row * 128 + ch * 8];
        }
        #pragma unroll
        for (int mt = 0; mt < 4; ++mt)
            #pragma unroll
            for (int nt = 0; nt < 4; ++nt)
                acc[mt][nt] = __builtin_amdgcn_mfma_f32_16x16x32_bf16(
                    af[mt], bf[nt][ks], acc[mt][nt], 0, 0, 0);
    }
    #pragma unroll
    for (int mt = 0; mt < 4; ++mt) {
        #pragma unroll
        for (int nt = 0; nt < 4; ++nt) {
            int colg = w * 64 + nt * 16 + (l & 15);
            #pragma unroll
            for (int r = 0; r < 4; ++r) {
                int rowg = r0 + mt * 16 + (l >> 4) * 4 + r;
                if (rowg < N) {
                    float val = acc[mt][nt][r];
                    if (colg < 128) xl[(size_t)rowg * 128 + colg] = f2bf(val);
                    else            xr[(size_t)rowg * 128 + (colg - 128)] = val;
                }
            }
        }
    }
}

// layer 1 fused, in-loop qe1 via fdot2 (wave per node, lane l owns channels
// 2l,2l+1). Depth-2 prefetch: src_perm two slots ahead, xl gather one ahead.
__global__ __launch_bounds__(256, 4) void k_fused1_dot(
    const int* __restrict__ rowptr, const int* __restrict__ src_perm,
    const ushort* __restrict__ xl_bf, const float* __restrict__ xr,
    const f16* __restrict__ ea_f16, const f16* __restrict__ we1h,
    const float* __restrict__ att,
    const float* __restrict__ Wl2, const float* __restrict__ Wr2,
    float* __restrict__ xl2, float* __restrict__ xr2, int N) {
    int t = threadIdx.x, l = t & 63;
    int n = (blockIdx.x * 256 + t) >> 6;
    if (n >= N) return;
    const float RLN2 = 1.44269504f;
    const unsigned* xlw = (const unsigned*)xl_bf;  // [node*64 + lane]
    // We1 k-pair registers: weX[kp] = (We1[2kp][2l], We1[2kp+1][2l]) etc.
    f16x2 weX[8], weY[8];
    #pragma unroll
    for (int kp = 0; kp < 8; ++kp) {
        weX[kp][0] = we1h[(2 * kp) * 128 + 2 * l];
        weX[kp][1] = we1h[(2 * kp + 1) * 128 + 2 * l];
        weY[kp][0] = we1h[(2 * kp) * 128 + 2 * l + 1];
        weY[kp][1] = we1h[(2 * kp + 1) * 128 + 2 * l + 1];
    }
    f32x2 av = *(const f32x2*)(att + 2 * l);
    av = av * RLN2;
    f32x2 xrv = *(const f32x2*)(xr + (size_t)n * 128 + 2 * l);
    int rs = rowptr[n], re = rowptr[n + 1];
    int deg = re - rs;
    int urs = __builtin_amdgcn_readfirstlane(rs);   // wave-uniform addressing
    f32x2 acc = {0.f, 0.f}, mq = {0.f, 0.f};
    float den = 0.f;
    auto body = [&](unsigned jj, unsigned xw) {
        const f16x2* ap = (const f16x2*)(ea_f16 + (size_t)jj * 16);  // uniform
        float qx = 0.f, qy = 0.f;
        #pragma unroll
        for (int kp = 0; kp < 8; ++kp) {
            f16x2 a = ap[kp];
            qx = __builtin_amdgcn_fdot2(a, weX[kp], qx, false);
            qy = __builtin_amdgcn_fdot2(a, weY[kp], qy, false);
        }
        f32x2 q = {qx, qy};
        f32x2 xlv;
        xlv.x = __uint_as_float(xw << 16);
        xlv.y = __uint_as_float(xw & 0xffff0000u);
        f32x2 v = xrv + q + xlv;
        f32x2 u = __builtin_elementwise_max(v, 0.2f * v);
        f32x2 pt = av * u;
        float p = row_sum16(pt.x + pt.y);
        float w = exp2f(p);
        acc += xlv * w;
        den += w;
        mq += q;
    };
    if (deg > 0) {
        int s_cur = src_perm[(unsigned)urs];                 // src for slot 0
        unsigned xw_nxt = xlw[(unsigned)s_cur * 64u + (unsigned)l];  // gather slot 0
        int dclamp = deg - 1;
        int s_ahead = src_perm[(unsigned)(urs + (1 < deg ? 1 : dclamp))];  // src slot 1
        for (int slot = 0; slot + 1 < deg; ++slot) {
            unsigned xw = xw_nxt;
            int s1 = s_ahead;
            int idx2 = slot + 2;
            idx2 = idx2 < deg ? idx2 : dclamp;               // clamped, branchless
            s_ahead = src_perm[(unsigned)(urs + idx2)];      // src two ahead
            xw_nxt = xlw[(unsigned)s1 * 64u + (unsigned)l];  // gather one ahead
            body((unsigned)(urs + slot), xw);
        }
        body((unsigned)(urs + deg - 1), xw_nxt);
    }
    {   // self loop: q_self = mean of incoming q (= loop_attr @ We1)
        float inv = 1.f / (float)(deg > 1 ? deg : 1);
        f32x2 q = mq * inv;
        unsigned xw = xlw[(unsigned)n * 64u + (unsigned)l];
        f32x2 xlv;
        xlv.x = __uint_as_float(xw << 16);
        xlv.y = __uint_as_float(xw & 0xffff0000u);
        f32x2 v = xrv + q + xlv;
        f32x2 u = __builtin_elementwise_max(v, 0.2f * v);
        f32x2 pt = av * u;
        float p = row_sum16(pt.x + pt.y);
        float w = exp2f(p);
        acc += xlv * w;
        den += w;
    }
    float rdn = 1.f / (den + 1e-16f);
    float h0 = acc.x * rdn, h1 = acc.y * rdn;
    h0 = h0 > 0.f ? h0 : 0.01f * h0;
    h1 = h1 > 0.f ? h1 : 0.01f * h1;
    float4 wla = *(const float4*)(Wl2 + (size_t)(2 * l) * 4);
    float4 wlb = *(const float4*)(Wl2 + (size_t)(2 * l + 1) * 4);
    float4 wra = *(const float4*)(Wr2 + (size_t)(2 * l) * 4);
    float4 wrb = *(const float4*)(Wr2 + (size_t)(2 * l + 1) * 4);
    float q0 = red64(h0 * wla.x + h1 * wlb.x);
    float q1 = red64(h0 * wla.y + h1 * wlb.y);
    float q2 = red64(h0 * wla.z + h1 * wlb.z);
    float q3 = red64(h0 * wla.w + h1 * wlb.w);
    float q4 = red64(h0 * wra.x + h1 * wrb.x);
    float q5 = red64(h0 * wra.y + h1 * wrb.y);
    float q6 = red64(h0 * wra.z + h1 * wrb.z);
    float q7 = red64(h0 * wra.w + h1 * wrb.w);
    if (l == 0) {
        *(float4*)(xl2 + (size_t)n * 4) = make_float4(q0, q1, q2, q3);
        *(float4*)(xr2 + (size_t)n * 4) = make_float4(q4, q5, q6, q7);
    }
}

// layer 2 fused: 16 lanes per node, self-term = in-loop mean of qe2
__global__ __launch_bounds__(256, 4) void k_fused2_q(
    const int* __restrict__ rowptr, const int* __restrict__ src_perm,
    const float* __restrict__ xl2, const float* __restrict__ xr2,
    const float* __restrict__ qe2, const float* __restrict__ att2,
    float* __restrict__ out, int N) {
    int t = threadIdx.x, l = t & 63, g = l & 15;
    int node = (((blockIdx.x * 256 + t) >> 6) << 2) + (l >> 4);
    if (node >= N) return;
    int rs = rowptr[node], re = rowptr[node + 1];
    int deg = re - rs;
    float4 xrv = *(const float4*)(xr2 + (size_t)node * 4);
    const float RLN2 = 1.44269504f;
    float a0 = att2[0] * RLN2, a1 = att2[1] * RLN2;
    float a2 = att2[2] * RLN2, a3 = att2[3] * RLN2;
    float ac0 = 0.f, ac1 = 0.f, ac2 = 0.f, ac3 = 0.f;
    float dn0 = 0.f, dn1 = 0.f, dn2 = 0.f, dn3 = 0.f;
    float mq0 = 0.f, mq1 = 0.f, mq2 = 0.f, mq3 = 0.f;
    for (int slot = g; slot < deg; slot += 16) {
        int row = rs + slot;
        int s = src_perm[row];
        float4 q = *(const float4*)(qe2 + (size_t)row * 4);
        float4 xv = *(const float4*)(xl2 + (size_t)s * 4);
        float v0 = xv.x + xrv.x + q.x; v0 = fmaxf(v0, 0.2f * v0);
        float v1 = xv.y + xrv.y + q.y; v1 = fmaxf(v1, 0.2f * v1);
        float v2 = xv.z + xrv.z + q.z; v2 = fmaxf(v2, 0.2f * v2);
        float v3 = xv.w + xrv.w + q.w; v3 = fmaxf(v3, 0.2f * v3);
        float w0 = exp2f(v0 * a0); ac0 += w0 * xv.x; dn0 += w0;
        float w1 = exp2f(v1 * a1); ac1 += w1 * xv.y; dn1 += w1;
        float w2 = exp2f(v2 * a2); ac2 += w2 * xv.z; dn2 += w2;
        float w3 = exp2f(v3 * a3); ac3 += w3 * xv.w; dn3 += w3;
        mq0 += q.x; mq1 += q.y; mq2 += q.z; mq3 += q.w;
    }
    ac0 = row_sum16(ac0); ac1 = row_sum16(ac1);
    ac2 = row_sum16(ac2); ac3 = row_sum16(ac3);
    dn0 = row_sum16(dn0); dn1 = row_sum16(dn1);
    dn2 = row_sum16(dn2); dn3 = row_sum16(dn3);
    mq0 = row_sum16(mq0); mq1 = row_sum16(mq1);
    mq2 = row_sum16(mq2); mq3 = row_sum16(mq3);
    {   // self loop (uniform across the 16-lane group)
        float inv = 1.f / (float)(deg > 1 ? deg : 1);
        float4 xv = *(const float4*)(xl2 + (size_t)node * 4);
        float v0 = xv.x + xrv.x + mq0 * inv; v0 = fmaxf(v0, 0.2f * v0);
        float v1 = xv.y + xrv.y + mq1 * inv; v1 = fmaxf(v1, 0.2f * v1);
        float v2 = xv.z + xrv.z + mq2 * inv; v2 = fmaxf(v2, 0.2f * v2);
        float v3 = xv.w + xrv.w + mq3 * inv; v3 = fmaxf(v3, 0.2f * v3);
        float w0 = exp2f(v0 * a0); ac0 += w0 * xv.x; dn0 += w0;
        float w1 = exp2f(v1 * a1); ac1 += w1 * xv.y; dn1 += w1;
        float w2 = exp2f(v2 * a2); ac2 += w2 * xv.z; dn2 += w2;
        float w3 = exp2f(v3 * a3); ac3 += w3 * xv.w; dn3 += w3;
    }
    if (g == 0) {
        float r = ac0 / (dn0 + 1e-16f) + ac1 / (dn1 + 1e-16f)
                + ac2 / (dn2 + 1e-16f) + ac3 / (dn3 + 1e-16f);
        out[node] = r * 0.25f;
    }
}

extern "C" void kernel_launch(void* const* d_in, const int* in_sizes, int n_in,
                              void* d_out, int out_size, void* d_ws, size_t ws_size,
                              hipStream_t stream) {
    const float* x         = (const float*)d_in[0];
    const int*   edge_index= (const int*)d_in[1];
    const float* edge_attr = (const float*)d_in[2];
    const float* Wl1       = (const float*)d_in[3];
    const float* Wr1       = (const float*)d_in[4];
    const float* We1       = (const float*)d_in[5];
    const float* att1      = (const float*)d_in[6];
    const float* Wl2       = (const float*)d_in[7];
    const float* Wr2       = (const float*)d_in[8];
    const float* We2       = (const float*)d_in[9];
    const float* att2      = (const float*)d_in[10];
    float* outp = (float*)d_out;

    const int F = 128, HC = 128;
    int N = in_sizes[0] / F;
    int E = in_sizes[1] / 2;
    const int* src = edge_index;
    const int* dst = edge_index + E;

    char* ws = (char*)d_ws;
    size_t off = 0;
    auto alloc = [&](size_t bytes) {
        char* p = ws + off;
        off += (bytes + 255) & ~(size_t)255;
        return p;
    };
    int*      deg      = (int*)alloc((size_t)N * 4);
    int*      rowptr   = (int*)alloc((size_t)(N + 1) * 4);
    int*      part     = (int*)alloc(((size_t)N / 1024 + 2) * 4);
    int*      rank     = (int*)alloc((size_t)E * 4);
    ushort*   wcat_t   = (ushort*)alloc((size_t)128 * 256 * 2);
    f16*      we1h     = (f16*)alloc((size_t)16 * 128 * 2);
    ushort*   xl_bf    = (ushort*)alloc((size_t)N * HC * 2);
    float*    xr1      = (float*)alloc((size_t)N * HC * 4);
    float*    xl2      = (float*)alloc((size_t)N * 4 * 4);
    float*    xr2      = (float*)alloc((size_t)N * 4 * 4);
    int*      src_perm = (int*)alloc((size_t)E * 4);
    float*    qe2      = (float*)alloc((size_t)E * 4 * 4);
    f16*      ea_f16   = (f16*)alloc((size_t)E * 16 * 2);

    int eb = (E + 255) / 256;
    int nb = (N + 1023) / 1024;

    hipMemsetAsync(deg, 0, (size_t)N * 4, stream);
    k_count_deg<<<eb, 256, 0, stream>>>(dst, deg, rank, E);
    k_scan1<<<nb, 1024, 0, stream>>>(deg, rowptr, part, N);
    k_scan2<<<1, 64, 0, stream>>>(part, nb);
    k_scan3<<<(N + 255) / 256, 256, 0, stream>>>(rowptr, part, N, E);
    k_scatter_e<<<eb, 256, 0, stream>>>(dst, src, edge_attr, We2, rowptr, rank,
                                        ea_f16, qe2, src_perm, E);
    k_wcvt<<<128, 256, 0, stream>>>(Wl1, Wr1, We1, wcat_t, we1h);
    k_gemm1_mfma<<<(N + 63) / 64, 256, 0, stream>>>(x, wcat_t, xl_bf, xr1, N);
    k_fused1_dot<<<(N + 3) / 4, 256, 0, stream>>>(rowptr, src_perm, xl_bf, xr1, ea_f16,
                                                  we1h, att1, Wl2, Wr2, xl2, xr2, N);
    k_fused2_q<<<(N + 15) / 16, 256, 0, stream>>>(rowptr, src_perm, xl2, xr2, qe2,
                                                  att2, outp, N);
}

// Round 21
// 206.826 us; speedup vs baseline: 1.2043x; 1.0216x over previous
//
#include <hip/hip_runtime.h>
#include <math.h>

// ---------------------------------------------------------------------------
// GATv2 x2 on MI355X.  (Best configuration — round-18 structure.)
// Path:
//   memset(deg) -> k_count_deg (atomic rank capture) -> scan1/2/3
//   -> k_scatter_e (pos = rowptr+rank, atomic-free; ea_f16/qe2/src_perm)
//   -> k_wcvt (wcat transposed [n][k] bf16; we1h f16) -> k_gemm1_mfma
//   -> k_fused1_dot (in-loop qe1 via fdot2; xl gather software-pipelined
//      one slot ahead) -> k_fused2_q
// Round 21: r20's depth-2 prefetch reverted (clamp overhead > latency gain);
// back to r18's single-depth prefetch = best measured (207 us).
// ---------------------------------------------------------------------------

typedef __attribute__((ext_vector_type(8))) short bf16x8;
typedef __attribute__((ext_vector_type(4))) float f32x4;
typedef __attribute__((ext_vector_type(2))) float f32x2;
typedef _Float16 f16;
typedef __attribute__((ext_vector_type(2))) _Float16 f16x2;
typedef __attribute__((ext_vector_type(8))) _Float16 f16x8;

static __device__ __forceinline__ ushort f2bf(float f) {
    unsigned u = __float_as_uint(f);
    unsigned r = (u + 0x7fffu + ((u >> 16) & 1u)) >> 16;  // RNE
    return (ushort)r;
}

// sum across each 16-lane row via DPP row_ror (pure VALU, no DS)
static __device__ __forceinline__ float row_sum16(float x) {
    x += __int_as_float(__builtin_amdgcn_update_dpp(0, __float_as_int(x), 0x121, 0xf, 0xf, true));
    x += __int_as_float(__builtin_amdgcn_update_dpp(0, __float_as_int(x), 0x122, 0xf, 0xf, true));
    x += __int_as_float(__builtin_amdgcn_update_dpp(0, __float_as_int(x), 0x124, 0xf, 0xf, true));
    x += __int_as_float(__builtin_amdgcn_update_dpp(0, __float_as_int(x), 0x128, 0xf, 0xf, true));
    return x;
}

static __device__ __forceinline__ float red64(float x) {  // 64-lane sum
    x = row_sum16(x);
    x += __shfl_xor(x, 16);
    x += __shfl_xor(x, 32);
    return x;
}

// rank[i] = arrival order of edge i at its destination (used as CSR offset)
__global__ void k_count_deg(const int* __restrict__ dst, int* __restrict__ deg,
                            int* __restrict__ rank, int E) {
    int i = blockIdx.x * blockDim.x + threadIdx.x;
    if (i < E) rank[i] = atomicAdd(&deg[dst[i]], 1);
}

__global__ __launch_bounds__(1024) void k_scan1(const int* __restrict__ deg,
                                                int* __restrict__ rowptr,
                                                int* __restrict__ part, int N) {
    __shared__ int wsum[16];
    int t = threadIdx.x, l = t & 63, w = t >> 6;
    int i = blockIdx.x * 1024 + t;
    int v = (i < N) ? deg[i] : 0;
    int sc = v;
    #pragma unroll
    for (int off = 1; off < 64; off <<= 1) {
        int y = __shfl_up(sc, off);
        if (l >= off) sc += y;
    }
    if (l == 63) wsum[w] = sc;
    __syncthreads();
    if (w == 0) {
        int pv = (l < 16) ? wsum[l] : 0;
        int psc = pv;
        #pragma unroll
        for (int off = 1; off < 16; off <<= 1) {
            int y = __shfl_up(psc, off);
            if (l >= off) psc += y;
        }
        if (l < 16) wsum[l] = psc - pv;
    }
    __syncthreads();
    if (i < N) rowptr[i] = wsum[w] + sc - v;
    if (t == 1023) part[blockIdx.x] = wsum[15] + sc;
}

__global__ void k_scan2(int* __restrict__ part, int nb) {
    int l = threadIdx.x & 63;
    int run = 0;
    for (int base = 0; base < nb; base += 64) {
        int i = base + l;
        int v = (i < nb) ? part[i] : 0;
        int sc = v;
        #pragma unroll
        for (int off = 1; off < 64; off <<= 1) {
            int y = __shfl_up(sc, off);
            if (l >= off) sc += y;
        }
        if (i < nb) part[i] = run + sc - v;
        run += __shfl(sc, 63);
    }
}

__global__ void k_scan3(int* __restrict__ rowptr, const int* __restrict__ part, int N, int E) {
    int i = blockIdx.x * 256 + threadIdx.x;
    if (i < N) rowptr[i] += part[i >> 10];
    if (i == 0) rowptr[N] = E;
}

// scatter edges to CSR positions (pos = rowptr[dst] + rank, atomic-free):
// ea_f16[pos] (f16 x16), qe2[pos] = ea@We2 (f32 x4), src_perm[pos] = src.
__global__ __launch_bounds__(256) void k_scatter_e(
    const int* __restrict__ dst, const int* __restrict__ src,
    const float* __restrict__ ea, const float* __restrict__ We2,
    const int* __restrict__ rowptr, const int* __restrict__ rank,
    f16* __restrict__ ea_f16, float* __restrict__ qe2,
    int* __restrict__ src_perm, int E) {
    __shared__ float sW[64];
    int t = threadIdx.x;
    if (t < 64) sW[t] = We2[t];
    __syncthreads();
    int i = blockIdx.x * 256 + t;
    if (i >= E) return;
    int d = dst[i];
    int pos = rowptr[d] + rank[i];
    src_perm[pos] = src[i];
    const float4* s4 = (const float4*)(ea + (size_t)i * 16);
    float4 r0 = s4[0], r1 = s4[1], r2 = s4[2], r3 = s4[3];
    f16x8 h0, h1;
    h0[0] = (f16)r0.x; h0[1] = (f16)r0.y; h0[2] = (f16)r0.z; h0[3] = (f16)r0.w;
    h0[4] = (f16)r1.x; h0[5] = (f16)r1.y; h0[6] = (f16)r1.z; h0[7] = (f16)r1.w;
    h1[0] = (f16)r2.x; h1[1] = (f16)r2.y; h1[2] = (f16)r2.z; h1[3] = (f16)r2.w;
    h1[4] = (f16)r3.x; h1[5] = (f16)r3.y; h1[6] = (f16)r3.z; h1[7] = (f16)r3.w;
    *(f16x8*)(ea_f16 + (size_t)pos * 16) = h0;
    *(f16x8*)(ea_f16 + (size_t)pos * 16 + 8) = h1;
    float a[16] = {r0.x, r0.y, r0.z, r0.w, r1.x, r1.y, r1.z, r1.w,
                   r2.x, r2.y, r2.z, r2.w, r3.x, r3.y, r3.z, r3.w};
    float q0 = 0.f, q1 = 0.f, q2v = 0.f, q3 = 0.f;
    #pragma unroll
    for (int k = 0; k < 16; ++k) {
        q0 += a[k] * sW[k * 4 + 0];
        q1 += a[k] * sW[k * 4 + 1];
        q2v += a[k] * sW[k * 4 + 2];
        q3 += a[k] * sW[k * 4 + 3];
    }
    *(float4*)(qe2 + (size_t)pos * 4) = make_float4(q0, q1, q2v, q3);
}

// wcat_t[n][k] (bf16, 256x128) = [Wl1 | Wr1]^T; we1h = f16 We1 (16x128)
__global__ void k_wcvt(const float* __restrict__ Wl, const float* __restrict__ Wr,
                       const float* __restrict__ We1,
                       ushort* __restrict__ wcat_t, f16* __restrict__ we1h) {
    int i = blockIdx.x * 256 + threadIdx.x;
    if (i < 16 * 128) we1h[i] = (f16)We1[i];
    if (i >= 128 * 256) return;
    int n = i >> 7, k = i & 127;
    float v = (n < 128) ? Wl[k * 128 + n] : Wr[k * 128 + (n - 128)];
    wcat_t[i] = f2bf(v);
}

// xl1 = x@Wl1 (bf16 out), xr1 = x@Wr1 (f32 out) via MFMA bf16.
__global__ __launch_bounds__(256) void k_gemm1_mfma(
    const float* __restrict__ x, const ushort* __restrict__ wcat_t,
    ushort* __restrict__ xl, float* __restrict__ xr, int N) {
    __shared__ ushort xs[64 * 128];  // 16 KB, swizzled
    int t = threadIdx.x, l = t & 63, w = t >> 6;
    int r0 = blockIdx.x * 64;
    bf16x8 bf[4][4];
    {
        int coln = w * 64 + (l & 15);
        int kr = (l >> 4) * 8;
        #pragma unroll
        for (int nt = 0; nt < 4; ++nt)
            #pragma unroll
            for (int ks = 0; ks < 4; ++ks)
                bf[nt][ks] = *(const bf16x8*)&wcat_t[(size_t)(nt * 16 + coln) * 128 + ks * 32 + kr];
    }
    #pragma unroll
    for (int it = 0; it < 4; ++it) {
        int slot = t + 256 * it;        // 1024 slots = 64 rows x 16 chunks
        int row = slot >> 4, ch = slot & 15;
        int grow = r0 + row;
        float v0 = 0.f, v1 = 0.f, v2 = 0.f, v3 = 0.f, v4 = 0.f, v5 = 0.f, v6 = 0.f, v7 = 0.f;
        if (grow < N) {
            float4 a = *(const float4*)(x + (size_t)grow * 128 + ch * 8);
            float4 b = *(const float4*)(x + (size_t)grow * 128 + ch * 8 + 4);
            v0 = a.x; v1 = a.y; v2 = a.z; v3 = a.w;
            v4 = b.x; v5 = b.y; v6 = b.z; v7 = b.w;
        }
        bf16x8 tv;
        tv[0] = (short)f2bf(v0); tv[1] = (short)f2bf(v1);
        tv[2] = (short)f2bf(v2); tv[3] = (short)f2bf(v3);
        tv[4] = (short)f2bf(v4); tv[5] = (short)f2bf(v5);
        tv[6] = (short)f2bf(v6); tv[7] = (short)f2bf(v7);
        int ch2 = ch ^ (row & 15);
        *(bf16x8*)&xs[row * 128 + ch2 * 8] = tv;
    }
    __syncthreads();
    f32x4 acc[4][4];
    #pragma unroll
    for (int mt = 0; mt < 4; ++mt)
        #pragma unroll
        for (int nt = 0; nt < 4; ++nt)
            acc[mt][nt] = (f32x4){0.f, 0.f, 0.f, 0.f};
    #pragma unroll
    for (int ks = 0; ks < 4; ++ks) {
        bf16x8 af[4];
        #pragma unroll
        for (int mt = 0; mt < 4; ++mt) {
            int row = mt * 16 + (l & 15);
            int ch = (ks * 4 + (l >> 4)) ^ (row & 15);
            af[mt] = *(const bf16x8*)&xs[row * 128 + ch * 8];
        }
        #pragma unroll
        for (int mt = 0; mt < 4; ++mt)
            #pragma unroll
            for (int nt = 0; nt < 4; ++nt)
                acc[mt][nt] = __builtin_amdgcn_mfma_f32_16x16x32_bf16(
                    af[mt], bf[nt][ks], acc[mt][nt], 0, 0, 0);
    }
    #pragma unroll
    for (int mt = 0; mt < 4; ++mt) {
        #pragma unroll
        for (int nt = 0; nt < 4; ++nt) {
            int colg = w * 64 + nt * 16 + (l & 15);
            #pragma unroll
            for (int r = 0; r < 4; ++r) {
                int rowg = r0 + mt * 16 + (l >> 4) * 4 + r;
                if (rowg < N) {
                    float val = acc[mt][nt][r];
                    if (colg < 128) xl[(size_t)rowg * 128 + colg] = f2bf(val);
                    else            xr[(size_t)rowg * 128 + (colg - 128)] = val;
                }
            }
        }
    }
}

// layer 1 fused, in-loop qe1 via fdot2 (wave per node, lane l owns channels
// 2l,2l+1). xl gather software-pipelined one slot ahead.
__global__ __launch_bounds__(256, 4) void k_fused1_dot(
    const int* __restrict__ rowptr, const int* __restrict__ src_perm,
    const ushort* __restrict__ xl_bf, const float* __restrict__ xr,
    const f16* __restrict__ ea_f16, const f16* __restrict__ we1h,
    const float* __restrict__ att,
    const float* __restrict__ Wl2, const float* __restrict__ Wr2,
    float* __restrict__ xl2, float* __restrict__ xr2, int N) {
    int t = threadIdx.x, l = t & 63;
    int n = (blockIdx.x * 256 + t) >> 6;
    if (n >= N) return;
    const float RLN2 = 1.44269504f;
    const unsigned* xlw = (const unsigned*)xl_bf;  // [node*64 + lane]
    // We1 k-pair registers: weX[kp] = (We1[2kp][2l], We1[2kp+1][2l]) etc.
    f16x2 weX[8], weY[8];
    #pragma unroll
    for (int kp = 0; kp < 8; ++kp) {
        weX[kp][0] = we1h[(2 * kp) * 128 + 2 * l];
        weX[kp][1] = we1h[(2 * kp + 1) * 128 + 2 * l];
        weY[kp][0] = we1h[(2 * kp) * 128 + 2 * l + 1];
        weY[kp][1] = we1h[(2 * kp + 1) * 128 + 2 * l + 1];
    }
    f32x2 av = *(const f32x2*)(att + 2 * l);
    av = av * RLN2;
    f32x2 xrv = *(const f32x2*)(xr + (size_t)n * 128 + 2 * l);
    int rs = rowptr[n], re = rowptr[n + 1];
    int deg = re - rs;
    int urs = __builtin_amdgcn_readfirstlane(rs);   // wave-uniform addressing
    f32x2 acc = {0.f, 0.f}, mq = {0.f, 0.f};
    float den = 0.f;
    auto body = [&](unsigned jj, unsigned xw) {
        const f16x2* ap = (const f16x2*)(ea_f16 + (size_t)jj * 16);  // uniform
        float qx = 0.f, qy = 0.f;
        #pragma unroll
        for (int kp = 0; kp < 8; ++kp) {
            f16x2 a = ap[kp];
            qx = __builtin_amdgcn_fdot2(a, weX[kp], qx, false);
            qy = __builtin_amdgcn_fdot2(a, weY[kp], qy, false);
        }
        f32x2 q = {qx, qy};
        f32x2 xlv;
        xlv.x = __uint_as_float(xw << 16);
        xlv.y = __uint_as_float(xw & 0xffff0000u);
        f32x2 v = xrv + q + xlv;
        f32x2 u = __builtin_elementwise_max(v, 0.2f * v);
        f32x2 pt = av * u;
        float p = row_sum16(pt.x + pt.y);
        float w = exp2f(p);
        acc += xlv * w;
        den += w;
        mq += q;
    };
    if (deg > 0) {
        int s0 = src_perm[(unsigned)urs];
        unsigned xw_nxt = xlw[(unsigned)s0 * 64u + (unsigned)l];
        for (int slot = 0; slot + 1 < deg; ++slot) {
            unsigned xw = xw_nxt;
            int s1 = src_perm[(unsigned)(urs + slot + 1)];
            xw_nxt = xlw[(unsigned)s1 * 64u + (unsigned)l];  // lands next iter
            body((unsigned)(urs + slot), xw);
        }
        body((unsigned)(urs + deg - 1), xw_nxt);
    }
    {   // self loop: q_self = mean of incoming q (= loop_attr @ We1)
        float inv = 1.f / (float)(deg > 1 ? deg : 1);
        f32x2 q = mq * inv;
        unsigned xw = xlw[(unsigned)n * 64u + (unsigned)l];
        f32x2 xlv;
        xlv.x = __uint_as_float(xw << 16);
        xlv.y = __uint_as_float(xw & 0xffff0000u);
        f32x2 v = xrv + q + xlv;
        f32x2 u = __builtin_elementwise_max(v, 0.2f * v);
        f32x2 pt = av * u;
        float p = row_sum16(pt.x + pt.y);
        float w = exp2f(p);
        acc += xlv * w;
        den += w;
    }
    float rdn = 1.f / (den + 1e-16f);
    float h0 = acc.x * rdn, h1 = acc.y * rdn;
    h0 = h0 > 0.f ? h0 : 0.01f * h0;
    h1 = h1 > 0.f ? h1 : 0.01f * h1;
    float4 wla = *(const float4*)(Wl2 + (size_t)(2 * l) * 4);
    float4 wlb = *(const float4*)(Wl2 + (size_t)(2 * l + 1) * 4);
    float4 wra = *(const float4*)(Wr2 + (size_t)(2 * l) * 4);
    float4 wrb = *(const float4*)(Wr2 + (size_t)(2 * l + 1) * 4);
    float q0 = red64(h0 * wla.x + h1 * wlb.x);
    float q1 = red64(h0 * wla.y + h1 * wlb.y);
    float q2 = red64(h0 * wla.z + h1 * wlb.z);
    float q3 = red64(h0 * wla.w + h1 * wlb.w);
    float q4 = red64(h0 * wra.x + h1 * wrb.x);
    float q5 = red64(h0 * wra.y + h1 * wrb.y);
    float q6 = red64(h0 * wra.z + h1 * wrb.z);
    float q7 = red64(h0 * wra.w + h1 * wrb.w);
    if (l == 0) {
        *(float4*)(xl2 + (size_t)n * 4) = make_float4(q0, q1, q2, q3);
        *(float4*)(xr2 + (size_t)n * 4) = make_float4(q4, q5, q6, q7);
    }
}

// layer 2 fused: 16 lanes per node, self-term = in-loop mean of qe2
__global__ __launch_bounds__(256, 4) void k_fused2_q(
    const int* __restrict__ rowptr, const int* __restrict__ src_perm,
    const float* __restrict__ xl2, const float* __restrict__ xr2,
    const float* __restrict__ qe2, const float* __restrict__ att2,
    float* __restrict__ out, int N) {
    int t = threadIdx.x, l = t & 63, g = l & 15;
    int node = (((blockIdx.x * 256 + t) >> 6) << 2) + (l >> 4);
    if (node >= N) return;
    int rs = rowptr[node], re = rowptr[node + 1];
    int deg = re - rs;
    float4 xrv = *(const float4*)(xr2 + (size_t)node * 4);
    const float RLN2 = 1.44269504f;
    float a0 = att2[0] * RLN2, a1 = att2[1] * RLN2;
    float a2 = att2[2] * RLN2, a3 = att2[3] * RLN2;
    float ac0 = 0.f, ac1 = 0.f, ac2 = 0.f, ac3 = 0.f;
    float dn0 = 0.f, dn1 = 0.f, dn2 = 0.f, dn3 = 0.f;
    float mq0 = 0.f, mq1 = 0.f, mq2 = 0.f, mq3 = 0.f;
    for (int slot = g; slot < deg; slot += 16) {
        int row = rs + slot;
        int s = src_perm[row];
        float4 q = *(const float4*)(qe2 + (size_t)row * 4);
        float4 xv = *(const float4*)(xl2 + (size_t)s * 4);
        float v0 = xv.x + xrv.x + q.x; v0 = fmaxf(v0, 0.2f * v0);
        float v1 = xv.y + xrv.y + q.y; v1 = fmaxf(v1, 0.2f * v1);
        float v2 = xv.z + xrv.z + q.z; v2 = fmaxf(v2, 0.2f * v2);
        float v3 = xv.w + xrv.w + q.w; v3 = fmaxf(v3, 0.2f * v3);
        float w0 = exp2f(v0 * a0); ac0 += w0 * xv.x; dn0 += w0;
        float w1 = exp2f(v1 * a1); ac1 += w1 * xv.y; dn1 += w1;
        float w2 = exp2f(v2 * a2); ac2 += w2 * xv.z; dn2 += w2;
        float w3 = exp2f(v3 * a3); ac3 += w3 * xv.w; dn3 += w3;
        mq0 += q.x; mq1 += q.y; mq2 += q.z; mq3 += q.w;
    }
    ac0 = row_sum16(ac0); ac1 = row_sum16(ac1);
    ac2 = row_sum16(ac2); ac3 = row_sum16(ac3);
    dn0 = row_sum16(dn0); dn1 = row_sum16(dn1);
    dn2 = row_sum16(dn2); dn3 = row_sum16(dn3);
    mq0 = row_sum16(mq0); mq1 = row_sum16(mq1);
    mq2 = row_sum16(mq2); mq3 = row_sum16(mq3);
    {   // self loop (uniform across the 16-lane group)
        float inv = 1.f / (float)(deg > 1 ? deg : 1);
        float4 xv = *(const float4*)(xl2 + (size_t)node * 4);
        float v0 = xv.x + xrv.x + mq0 * inv; v0 = fmaxf(v0, 0.2f * v0);
        float v1 = xv.y + xrv.y + mq1 * inv; v1 = fmaxf(v1, 0.2f * v1);
        float v2 = xv.z + xrv.z + mq2 * inv; v2 = fmaxf(v2, 0.2f * v2);
        float v3 = xv.w + xrv.w + mq3 * inv; v3 = fmaxf(v3, 0.2f * v3);
        float w0 = exp2f(v0 * a0); ac0 += w0 * xv.x; dn0 += w0;
        float w1 = exp2f(v1 * a1); ac1 += w1 * xv.y; dn1 += w1;
        float w2 = exp2f(v2 * a2); ac2 += w2 * xv.z; dn2 += w2;
        float w3 = exp2f(v3 * a3); ac3 += w3 * xv.w; dn3 += w3;
    }
    if (g == 0) {
        float r = ac0 / (dn0 + 1e-16f) + ac1 / (dn1 + 1e-16f)
                + ac2 / (dn2 + 1e-16f) + ac3 / (dn3 + 1e-16f);
        out[node] = r * 0.25f;
    }
}

extern "C" void kernel_launch(void* const* d_in, const int* in_sizes, int n_in,
                              void* d_out, int out_size, void* d_ws, size_t ws_size,
                              hipStream_t stream) {
    const float* x         = (const float*)d_in[0];
    const int*   edge_index= (const int*)d_in[1];
    const float* edge_attr = (const float*)d_in[2];
    const float* Wl1       = (const float*)d_in[3];
    const float* Wr1       = (const float*)d_in[4];
    const float* We1       = (const float*)d_in[5];
    const float* att1      = (const float*)d_in[6];
    const float* Wl2       = (const float*)d_in[7];
    const float* Wr2       = (const float*)d_in[8];
    const float* We2       = (const float*)d_in[9];
    const float* att2      = (const float*)d_in[10];
    float* outp = (float*)d_out;

    const int F = 128, HC = 128;
    int N = in_sizes[0] / F;
    int E = in_sizes[1] / 2;
    const int* src = edge_index;
    const int* dst = edge_index + E;

    char* ws = (char*)d_ws;
    size_t off = 0;
    auto alloc = [&](size_t bytes) {
        char* p = ws + off;
        off += (bytes + 255) & ~(size_t)255;
        return p;
    };
    int*      deg      = (int*)alloc((size_t)N * 4);
    int*      rowptr   = (int*)alloc((size_t)(N + 1) * 4);
    int*      part     = (int*)alloc(((size_t)N / 1024 + 2) * 4);
    int*      rank     = (int*)alloc((size_t)E * 4);
    ushort*   wcat_t   = (ushort*)alloc((size_t)128 * 256 * 2);
    f16*      we1h     = (f16*)alloc((size_t)16 * 128 * 2);
    ushort*   xl_bf    = (ushort*)alloc((size_t)N * HC * 2);
    float*    xr1      = (float*)alloc((size_t)N * HC * 4);
    float*    xl2      = (float*)alloc((size_t)N * 4 * 4);
    float*    xr2      = (float*)alloc((size_t)N * 4 * 4);
    int*      src_perm = (int*)alloc((size_t)E * 4);
    float*    qe2      = (float*)alloc((size_t)E * 4 * 4);
    f16*      ea_f16   = (f16*)alloc((size_t)E * 16 * 2);

    int eb = (E + 255) / 256;
    int nb = (N + 1023) / 1024;

    hipMemsetAsync(deg, 0, (size_t)N * 4, stream);
    k_count_deg<<<eb, 256, 0, stream>>>(dst, deg, rank, E);
    k_scan1<<<nb, 1024, 0, stream>>>(deg, rowptr, part, N);
    k_scan2<<<1, 64, 0, stream>>>(part, nb);
    k_scan3<<<(N + 255) / 256, 256, 0, stream>>>(rowptr, part, N, E);
    k_scatter_e<<<eb, 256, 0, stream>>>(dst, src, edge_attr, We2, rowptr, rank,
                                        ea_f16, qe2, src_perm, E);
    k_wcvt<<<128, 256, 0, stream>>>(Wl1, Wr1, We1, wcat_t, we1h);
    k_gemm1_mfma<<<(N + 63) / 64, 256, 0, stream>>>(x, wcat_t, xl_bf, xr1, N);
    k_fused1_dot<<<(N + 3) / 4, 256, 0, stream>>>(rowptr, src_perm, xl_bf, xr1, ea_f16,
                                                  we1h, att1, Wl2, Wr2, xl2, xr2, N);
    k_fused2_q<<<(N + 15) / 16, 256, 0, stream>>>(rowptr, src_perm, xl2, xr2, qe2,
                                                  att2, outp, N);
}